// Round 3
// baseline (528.813 us; speedup 1.0000x reference)
//
#include <hip/hip_runtime.h>
#include <hip/hip_bf16.h>
#include <math.h>

typedef __attribute__((ext_vector_type(4))) float  f32x4;
typedef __attribute__((ext_vector_type(4))) int    i32x4;
typedef __attribute__((ext_vector_type(8))) short  s16x8;
typedef __attribute__((ext_vector_type(4))) short  s16x4;
typedef __attribute__((ext_vector_type(8))) __bf16 bf16x8;

#define LOG2E 1.4426950408889634f

__device__ __forceinline__ short f32_to_bf16_rne(float f) {
    unsigned u = __builtin_bit_cast(unsigned, f);
    u += 0x7fffu + ((u >> 16) & 1u);
    return (short)(u >> 16);
}
__device__ __forceinline__ bf16x8 as_bf16x8(s16x8 v) {
    return __builtin_bit_cast(bf16x8, v);
}

// ---------------- k0: W (f32 [k][col]) -> WT bf16 [col][k] ----------------
__global__ void k0_wt(const float* __restrict__ W, short* __restrict__ WT) {
    int g = blockIdx.x * 256 + threadIdx.x;     // 0..8191
    int col = g >> 6;
    int k0 = (g & 63) * 4;
    s16x4 v;
    #pragma unroll
    for (int i = 0; i < 4; ++i) v[i] = f32_to_bf16_rne(W[(k0 + i) * 128 + col]);
    *(s16x4*)(WT + col * 256 + k0) = v;
}

// ---------------- k1: Wh = h@W (MFMA), emit WhT bf16 [b][col][n], Wh1', Wh2' ----------------
__global__ __launch_bounds__(256, 2) void k1_gemm(
    const float* __restrict__ h, const float* __restrict__ a,
    const short* __restrict__ WT,
    short* __restrict__ WhT, float* __restrict__ Wh1p, float* __restrict__ Tp)
{
    int l = threadIdx.x & 63;
    int w = threadIdx.x >> 6;
    int gw = blockIdx.x * 4 + w;
    int r0 = gw * 16;                  // global row base (b*4096+n), multiple of 16
    int lm = l & 15, q = l >> 4;

    f32x4 acc[8];
    #pragma unroll
    for (int ct = 0; ct < 8; ++ct) acc[ct] = (f32x4)0.0f;

    const float* hrow = h + (long)(r0 + lm) * 256;
    for (int kb = 0; kb < 8; ++kb) {
        int kbase = kb * 32 + q * 8;
        f32x4 h0 = *(const f32x4*)(hrow + kbase);
        f32x4 h1 = *(const f32x4*)(hrow + kbase + 4);
        s16x8 af;
        #pragma unroll
        for (int j = 0; j < 4; ++j) af[j] = f32_to_bf16_rne(h0[j]);
        #pragma unroll
        for (int j = 0; j < 4; ++j) af[4 + j] = f32_to_bf16_rne(h1[j]);
        bf16x8 afb = as_bf16x8(af);
        #pragma unroll
        for (int ct = 0; ct < 8; ++ct) {
            s16x8 bf = *(const s16x8*)(WT + (ct * 16 + lm) * 256 + kbase);
            acc[ct] = __builtin_amdgcn_mfma_f32_16x16x32_bf16(afb, as_bf16x8(bf), acc[ct], 0, 0, 0);
        }
    }

    int b = r0 >> 12;
    int nb = r0 & 4095;
    float p1[4] = {0.f, 0.f, 0.f, 0.f}, p2[4] = {0.f, 0.f, 0.f, 0.f};
    #pragma unroll
    for (int ct = 0; ct < 8; ++ct) {
        int col = ct * 16 + lm;
        float a1c = a[col], a2c = a[128 + col];
        s16x4 vv;
        #pragma unroll
        for (int r = 0; r < 4; ++r) {
            float v = acc[ct][r];
            p1[r] += v * a1c;
            p2[r] += v * a2c;
            vv[r] = f32_to_bf16_rne(v);
        }
        *(s16x4*)(WhT + ((long)(b * 128 + col) * 4096 + nb + q * 4)) = vv;
    }
    #pragma unroll
    for (int off = 1; off < 16; off <<= 1) {
        #pragma unroll
        for (int r = 0; r < 4; ++r) {
            p1[r] += __shfl_xor(p1[r], off);
            p2[r] += __shfl_xor(p2[r], off);
        }
    }
    if (lm == 0) {
        #pragma unroll
        for (int r = 0; r < 4; ++r) {
            int row = r0 + q * 4 + r;
            Wh1p[row] = LOG2E * p1[r];
            Tp[row]   = LOG2E * p2[r];
        }
    }
}

// ---------------- k2: per-batch max of Tp ----------------
__global__ void k2_tmax(const float* __restrict__ Tp, float* __restrict__ Tmax) {
    __shared__ float red[256];
    int b = blockIdx.x, t = threadIdx.x;
    float mx = -1e30f;
    for (int i = 0; i < 16; ++i) mx = fmaxf(mx, Tp[b * 4096 + t + i * 256]);
    red[t] = mx;
    __syncthreads();
    for (int s = 128; s > 0; s >>= 1) {
        if (t < s) red[t] = fmaxf(red[t], red[t + s]);
        __syncthreads();
    }
    if (t == 0) Tmax[b] = red[0];
}

// ---------------- k3: barrier-free reg-pipelined attention @ Wh ----------------
// wave = 32 rows x 1024 m-slice; B-frags loaded straight from L2 into VGPRs.
template <int SPLIT>
__global__ __launch_bounds__(256, 2) void k3_attn(
    const int* __restrict__ adj, const short* __restrict__ WhT,
    const float* __restrict__ Wh1p, const float* __restrict__ Tp,
    const float* __restrict__ Tmax,
    float* __restrict__ U, float* __restrict__ Z)
{
    int l = threadIdx.x & 63, w = threadIdx.x >> 6;
    int lm = l & 15, q = l >> 4;
    int bid = blockIdx.x;
    int b  = bid >> 7;          // 4 batches x 128 rowgroups
    int rg = bid & 127;
    int r0 = rg * 32;
    int mh = w;                  // wave id = m-slice
    const int MSLICE = 4096 / SPLIT;     // 1024
    const int CHUNKS = MSLICE / 32;      // 32
    int M0 = mh * MSLICE;

    int row0 = r0 + lm, row1 = r0 + 16 + lm;
    float sp0 = Wh1p[b * 4096 + row0];
    float sp1 = Wh1p[b * 4096 + row1];
    float tmx = Tmax[b];
    float xm0 = sp0 + tmx, xm1 = sp1 + tmx;
    float M0r = fmaxf(xm0, 0.2f * xm0);
    float M1r = fmaxf(xm1, 0.2f * xm1);

    const int*   adjr0 = adj + ((long)(b * 4096 + row0) << 12) + q * 8;
    const int*   adjr1 = adj + ((long)(b * 4096 + row1) << 12) + q * 8;
    const float* tpb   = Tp + b * 4096 + q * 8;
    const short* whtb  = WhT + (long)b * 128 * 4096 + q * 8 + lm * 4096;

    f32x4 acc0[8], acc1[8];
    #pragma unroll
    for (int ct = 0; ct < 8; ++ct) { acc0[ct] = (f32x4)0.0f; acc1[ct] = (f32x4)0.0f; }
    float z0 = 0.0f, z1 = 0.0f;

    struct Chunk {
        s16x8 bf[8];
        i32x4 a0[2], a1[2];
        f32x4 t[2];
    };

    auto loadChunk = [&](Chunk& c, int m0) {
        #pragma unroll
        for (int ct = 0; ct < 8; ++ct)
            c.bf[ct] = *(const s16x8*)(whtb + ct * 16 * 4096 + m0);
        c.a0[0] = *(const i32x4*)(adjr0 + m0);
        c.a0[1] = *(const i32x4*)(adjr0 + m0 + 4);
        c.a1[0] = *(const i32x4*)(adjr1 + m0);
        c.a1[1] = *(const i32x4*)(adjr1 + m0 + 4);
        c.t[0]  = *(const f32x4*)(tpb + m0);
        c.t[1]  = *(const f32x4*)(tpb + m0 + 4);
    };

    auto computeChunk = [&](Chunk& c) {
        s16x8 a0f, a1f;
        float zz0 = 0.0f, zz1 = 0.0f;
        #pragma unroll
        for (int half = 0; half < 2; ++half) {
            i32x4 m0v = c.a0[half], m1v = c.a1[half];
            f32x4 t4 = c.t[half];
            #pragma unroll
            for (int j = 0; j < 4; ++j) {
                float tt = t4[j];
                float y0 = sp0 + tt;
                float e0 = fmaxf(y0, 0.2f * y0) - M0r;
                float w0 = __builtin_amdgcn_exp2f(e0);
                w0 = (m0v[j] != 0) ? w0 : 0.0f;
                zz0 += w0;
                a0f[half * 4 + j] = f32_to_bf16_rne(w0);
                float y1 = sp1 + tt;
                float e1 = fmaxf(y1, 0.2f * y1) - M1r;
                float w1 = __builtin_amdgcn_exp2f(e1);
                w1 = (m1v[j] != 0) ? w1 : 0.0f;
                zz1 += w1;
                a1f[half * 4 + j] = f32_to_bf16_rne(w1);
            }
        }
        z0 += zz0; z1 += zz1;
        bf16x8 a0b = as_bf16x8(a0f), a1b = as_bf16x8(a1f);
        #pragma unroll
        for (int ct = 0; ct < 8; ++ct) {
            bf16x8 bb = as_bf16x8(c.bf[ct]);
            acc0[ct] = __builtin_amdgcn_mfma_f32_16x16x32_bf16(a0b, bb, acc0[ct], 0, 0, 0);
            acc1[ct] = __builtin_amdgcn_mfma_f32_16x16x32_bf16(a1b, bb, acc1[ct], 0, 0, 0);
        }
    };

    Chunk cA, cB;
    loadChunk(cA, M0);
    #pragma unroll 1
    for (int c = 0; c < CHUNKS; c += 2) {
        loadChunk(cB, M0 + (c + 1) * 32);
        computeChunk(cA);
        int m2 = (c + 2 < CHUNKS) ? M0 + (c + 2) * 32 : M0;  // clamped harmless refetch
        loadChunk(cA, m2);
        computeChunk(cB);
    }

    // z reduction over q (lanes lm, lm+16, lm+32, lm+48 hold partials of same row)
    z0 += __shfl_xor(z0, 16); z0 += __shfl_xor(z0, 32);
    z1 += __shfl_xor(z1, 16); z1 += __shfl_xor(z1, 32);

    int slice = b * SPLIT + mh;
    if (l < 16) {
        Z[slice * 4096 + r0 + lm]      = z0;
        Z[slice * 4096 + r0 + 16 + lm] = z1;
    }
    float* ub = U + ((long)slice * 4096 + r0) * 128;
    #pragma unroll
    for (int ct = 0; ct < 8; ++ct) {
        int col = ct * 16 + lm;
        #pragma unroll
        for (int r = 0; r < 4; ++r) {
            ub[(q * 4 + r) * 128 + col]        = acc0[ct][r];
            ub[(16 + q * 4 + r) * 128 + col]   = acc1[ct][r];
        }
    }
}

// ---------------- k4: combine split-m quarters + ELU ----------------
__global__ void k4_combine(const float* __restrict__ U, const float* __restrict__ Z,
                           float* __restrict__ out) {
    long g = (long)blockIdx.x * 256 + threadIdx.x;   // float4 index
    long off = g * 4;
    long nf = off >> 7;                               // b*4096+n
    int b = (int)(nf >> 12), n = (int)(nf & 4095), col = (int)(off & 127);
    const long slice = (long)4096 * 128;
    long base0 = ((long)(b * 4) * 4096 + n) * 128 + col;
    f32x4 s = (f32x4)0.0f;
    float zz = 0.0f;
    #pragma unroll
    for (int i = 0; i < 4; ++i) {
        f32x4 u = *(const f32x4*)(U + base0 + i * slice);
        s += u;
        zz += Z[(b * 4 + i) * 4096 + n];
    }
    f32x4 v;
    #pragma unroll
    for (int i = 0; i < 4; ++i) {
        float x = s[i] / zz;
        v[i] = (x > 0.f) ? x : (expf(x) - 1.0f);
    }
    *(f32x4*)(out + off) = v;
}

extern "C" void kernel_launch(void* const* d_in, const int* in_sizes, int n_in,
                              void* d_out, int out_size, void* d_ws, size_t ws_size,
                              hipStream_t stream) {
    const float* h   = (const float*)d_in[0];
    const int*   adj = (const int*)d_in[1];
    const float* W   = (const float*)d_in[2];
    const float* a   = (const float*)d_in[3];
    float* out = (float*)d_out;

    char* ws = (char*)d_ws;
    short* WhT  = (short*)ws;                          // 4 MB  bf16 [b][col][n]
    short* WT   = (short*)(ws + 4194304);              // 64 KB bf16 [col][k]
    float* Wh1p = (float*)(ws + 4259840);              // 64 KB log2e*Wh@a1
    float* Tp   = (float*)(ws + 4325376);              // 64 KB log2e*Wh@a2
    float* Tmax = (float*)(ws + 4390912);              // 16 B (+pad)
    float* U    = (float*)(ws + 4391168);              // 32 MB (split=4)
    float* Z    = (float*)(ws + 4391168 + 33554432);   // 256 KB

    k0_wt<<<32, 256, 0, stream>>>(W, WT);
    k1_gemm<<<256, 256, 0, stream>>>(h, a, WT, WhT, Wh1p, Tp);
    k2_tmax<<<4, 256, 0, stream>>>(Tp, Tmax);
    k3_attn<4><<<512, 256, 0, stream>>>(adj, WhT, Wh1p, Tp, Tmax, U, Z);
    k4_combine<<<2048, 256, 0, stream>>>(U, Z, out);
    (void)in_sizes; (void)n_in; (void)out_size; (void)ws_size;
}

// Round 4
// 494.339 us; speedup vs baseline: 1.0697x; 1.0697x over previous
//
#include <hip/hip_runtime.h>
#include <hip/hip_bf16.h>
#include <math.h>

typedef __attribute__((ext_vector_type(4))) float  f32x4;
typedef __attribute__((ext_vector_type(4))) int    i32x4;
typedef __attribute__((ext_vector_type(8))) short  s16x8;
typedef __attribute__((ext_vector_type(4))) short  s16x4;
typedef __attribute__((ext_vector_type(8))) __bf16 bf16x8;

#define LOG2E 1.4426950408889634f

__device__ __forceinline__ short f32_to_bf16_rne(float f) {
    unsigned u = __builtin_bit_cast(unsigned, f);
    u += 0x7fffu + ((u >> 16) & 1u);
    return (short)(u >> 16);
}
__device__ __forceinline__ int pack2_bf16(float f0, float f1) {
    unsigned u0 = __builtin_bit_cast(unsigned, f0) + 0x8000u;   // round-half-up
    unsigned u1 = __builtin_bit_cast(unsigned, f1) + 0x8000u;
    return (int)((u0 >> 16) | (u1 & 0xffff0000u));
}
__device__ __forceinline__ bf16x8 as_bf16x8(s16x8 v) {
    return __builtin_bit_cast(bf16x8, v);
}
__device__ __forceinline__ bf16x8 as_bf16x8(i32x4 v) {
    return __builtin_bit_cast(bf16x8, v);
}

// ---------------- k0: W (f32 [k][col]) -> WT bf16 [col][k] ----------------
__global__ void k0_wt(const float* __restrict__ W, short* __restrict__ WT) {
    int g = blockIdx.x * 256 + threadIdx.x;     // 0..8191
    int col = g >> 6;
    int k0 = (g & 63) * 4;
    s16x4 v;
    #pragma unroll
    for (int i = 0; i < 4; ++i) v[i] = f32_to_bf16_rne(W[(k0 + i) * 128 + col]);
    *(s16x4*)(WT + col * 256 + k0) = v;
}

// ---------------- k1: Wh = h@W (MFMA), emit WhT bf16 [b][col][n], Wh1', Wh2' ----------------
__global__ __launch_bounds__(256, 2) void k1_gemm(
    const float* __restrict__ h, const float* __restrict__ a,
    const short* __restrict__ WT,
    short* __restrict__ WhT, float* __restrict__ Wh1p, float* __restrict__ Tp)
{
    int l = threadIdx.x & 63;
    int w = threadIdx.x >> 6;
    int gw = blockIdx.x * 4 + w;
    int r0 = gw * 16;                  // global row base (b*4096+n), multiple of 16
    int lm = l & 15, q = l >> 4;

    f32x4 acc[8];
    #pragma unroll
    for (int ct = 0; ct < 8; ++ct) acc[ct] = (f32x4)0.0f;

    const float* hrow = h + (long)(r0 + lm) * 256;
    for (int kb = 0; kb < 8; ++kb) {
        int kbase = kb * 32 + q * 8;
        f32x4 h0 = *(const f32x4*)(hrow + kbase);
        f32x4 h1 = *(const f32x4*)(hrow + kbase + 4);
        s16x8 af;
        #pragma unroll
        for (int j = 0; j < 4; ++j) af[j] = f32_to_bf16_rne(h0[j]);
        #pragma unroll
        for (int j = 0; j < 4; ++j) af[4 + j] = f32_to_bf16_rne(h1[j]);
        bf16x8 afb = as_bf16x8(af);
        #pragma unroll
        for (int ct = 0; ct < 8; ++ct) {
            s16x8 bf = *(const s16x8*)(WT + (ct * 16 + lm) * 256 + kbase);
            acc[ct] = __builtin_amdgcn_mfma_f32_16x16x32_bf16(afb, as_bf16x8(bf), acc[ct], 0, 0, 0);
        }
    }

    int b = r0 >> 12;
    int nb = r0 & 4095;
    float p1[4] = {0.f, 0.f, 0.f, 0.f}, p2[4] = {0.f, 0.f, 0.f, 0.f};
    #pragma unroll
    for (int ct = 0; ct < 8; ++ct) {
        int col = ct * 16 + lm;
        float a1c = a[col], a2c = a[128 + col];
        s16x4 vv;
        #pragma unroll
        for (int r = 0; r < 4; ++r) {
            float v = acc[ct][r];
            p1[r] += v * a1c;
            p2[r] += v * a2c;
            vv[r] = f32_to_bf16_rne(v);
        }
        *(s16x4*)(WhT + ((long)(b * 128 + col) * 4096 + nb + q * 4)) = vv;
    }
    #pragma unroll
    for (int off = 1; off < 16; off <<= 1) {
        #pragma unroll
        for (int r = 0; r < 4; ++r) {
            p1[r] += __shfl_xor(p1[r], off);
            p2[r] += __shfl_xor(p2[r], off);
        }
    }
    if (lm == 0) {
        #pragma unroll
        for (int r = 0; r < 4; ++r) {
            int row = r0 + q * 4 + r;
            Wh1p[row] = LOG2E * p1[r];
            Tp[row]   = LOG2E * p2[r];
        }
    }
}

// ---------------- k2: per-batch max of Tp ----------------
__global__ void k2_tmax(const float* __restrict__ Tp, float* __restrict__ Tmax) {
    __shared__ float red[256];
    int b = blockIdx.x, t = threadIdx.x;
    float mx = -1e30f;
    for (int i = 0; i < 16; ++i) mx = fmaxf(mx, Tp[b * 4096 + t + i * 256]);
    red[t] = mx;
    __syncthreads();
    for (int s = 128; s > 0; s >>= 1) {
        if (t < s) red[t] = fmaxf(red[t], red[t + s]);
        __syncthreads();
    }
    if (t == 0) Tmax[b] = red[0];
}

// ---------------- k3: barrier-free reg-pipelined attention @ Wh ----------------
// wave = 32 rows x 1024 m-slice. Pipeline forced via waves_per_eu(2,2)
// (pins scheduler's occupancy target -> keeps double-buffer in VGPRs) and
// sched_barrier(0) packet pins (loads issue ahead of independent compute).
template <int SPLIT>
__global__
__attribute__((amdgpu_flat_work_group_size(256, 256)))
__attribute__((amdgpu_waves_per_eu(2, 2)))
void k3_attn(
    const int* __restrict__ adj, const short* __restrict__ WhT,
    const float* __restrict__ Wh1p, const float* __restrict__ Tp,
    const float* __restrict__ Tmax,
    float* __restrict__ U, float* __restrict__ Z)
{
    int l = threadIdx.x & 63, w = threadIdx.x >> 6;
    int lm = l & 15, q = l >> 4;
    int bid = blockIdx.x;
    int b  = bid >> 7;          // 4 batches x 128 rowgroups
    int rg = bid & 127;
    int r0 = rg * 32;
    int mh = w;                  // wave id = m-slice
    const int MSLICE = 4096 / SPLIT;     // 1024
    const int CHUNKS = MSLICE / 32;      // 32
    int M0 = mh * MSLICE;

    int row0 = r0 + lm, row1 = r0 + 16 + lm;
    float sp0 = Wh1p[b * 4096 + row0];
    float sp1 = Wh1p[b * 4096 + row1];
    float tmx = Tmax[b];
    float xm0 = sp0 + tmx, xm1 = sp1 + tmx;
    float M0r = fmaxf(xm0, 0.2f * xm0);
    float M1r = fmaxf(xm1, 0.2f * xm1);

    const int*   adjr0 = adj + ((long)(b * 4096 + row0) << 12) + q * 8;
    const int*   adjr1 = adj + ((long)(b * 4096 + row1) << 12) + q * 8;
    const float* tpb   = Tp + b * 4096 + q * 8;
    const short* whtb  = WhT + (long)b * 128 * 4096 + q * 8 + lm * 4096;

    f32x4 acc0[8], acc1[8];
    #pragma unroll
    for (int ct = 0; ct < 8; ++ct) { acc0[ct] = (f32x4)0.0f; acc1[ct] = (f32x4)0.0f; }
    float z0 = 0.0f, z1 = 0.0f;

    struct Chunk {
        i32x4 a0[2], a1[2];     // adj rows (HBM — issue first)
        s16x8 bf[8];            // WhT B-frags (L2-hot)
        f32x4 t[2];             // Tp slice (L2-hot)
    };

    auto loadChunk = [&](Chunk& c, int m0) {
        c.a0[0] = *(const i32x4*)(adjr0 + m0);
        c.a0[1] = *(const i32x4*)(adjr0 + m0 + 4);
        c.a1[0] = *(const i32x4*)(adjr1 + m0);
        c.a1[1] = *(const i32x4*)(adjr1 + m0 + 4);
        #pragma unroll
        for (int ct = 0; ct < 8; ++ct)
            c.bf[ct] = *(const s16x8*)(whtb + ct * 16 * 4096 + m0);
        c.t[0]  = *(const f32x4*)(tpb + m0);
        c.t[1]  = *(const f32x4*)(tpb + m0 + 4);
    };

    auto computeChunk = [&](Chunk& c) {
        i32x4 p0, p1;
        float zz0 = 0.0f, zz1 = 0.0f;
        #pragma unroll
        for (int half = 0; half < 2; ++half) {
            i32x4 m0v = c.a0[half], m1v = c.a1[half];
            f32x4 t4 = c.t[half];
            float w0[4], w1[4];
            #pragma unroll
            for (int j = 0; j < 4; ++j) {
                float tt = t4[j];
                float y0 = sp0 + tt;
                float e0 = fmaxf(y0, 0.2f * y0) - M0r;
                float v0 = __builtin_amdgcn_exp2f(e0);
                v0 = (m0v[j] != 0) ? v0 : 0.0f;
                zz0 += v0; w0[j] = v0;
                float y1 = sp1 + tt;
                float e1 = fmaxf(y1, 0.2f * y1) - M1r;
                float v1 = __builtin_amdgcn_exp2f(e1);
                v1 = (m1v[j] != 0) ? v1 : 0.0f;
                zz1 += v1; w1[j] = v1;
            }
            p0[half * 2 + 0] = pack2_bf16(w0[0], w0[1]);
            p0[half * 2 + 1] = pack2_bf16(w0[2], w0[3]);
            p1[half * 2 + 0] = pack2_bf16(w1[0], w1[1]);
            p1[half * 2 + 1] = pack2_bf16(w1[2], w1[3]);
        }
        z0 += zz0; z1 += zz1;
        bf16x8 a0b = as_bf16x8(p0), a1b = as_bf16x8(p1);
        #pragma unroll
        for (int ct = 0; ct < 8; ++ct) {
            bf16x8 bb = as_bf16x8(c.bf[ct]);
            acc0[ct] = __builtin_amdgcn_mfma_f32_16x16x32_bf16(a0b, bb, acc0[ct], 0, 0, 0);
            acc1[ct] = __builtin_amdgcn_mfma_f32_16x16x32_bf16(a1b, bb, acc1[ct], 0, 0, 0);
        }
    };

    Chunk cA, cB;
    loadChunk(cA, M0);
    __builtin_amdgcn_sched_barrier(0);
    #pragma unroll 1
    for (int c = 0; c < CHUNKS; c += 2) {
        loadChunk(cB, M0 + (c + 1) * 32);
        __builtin_amdgcn_sched_barrier(0);
        computeChunk(cA);
        int m2 = (c + 2 < CHUNKS) ? M0 + (c + 2) * 32 : M0;  // clamped harmless refetch
        loadChunk(cA, m2);
        __builtin_amdgcn_sched_barrier(0);
        computeChunk(cB);
    }

    // z reduction over q (lanes lm, lm+16, lm+32, lm+48 hold partials of same row)
    z0 += __shfl_xor(z0, 16); z0 += __shfl_xor(z0, 32);
    z1 += __shfl_xor(z1, 16); z1 += __shfl_xor(z1, 32);

    int slice = b * SPLIT + mh;
    if (l < 16) {
        Z[slice * 4096 + r0 + lm]      = z0;
        Z[slice * 4096 + r0 + 16 + lm] = z1;
    }
    float* ub = U + ((long)slice * 4096 + r0) * 128;
    #pragma unroll
    for (int ct = 0; ct < 8; ++ct) {
        int col = ct * 16 + lm;
        #pragma unroll
        for (int r = 0; r < 4; ++r) {
            ub[(q * 4 + r) * 128 + col]        = acc0[ct][r];
            ub[(16 + q * 4 + r) * 128 + col]   = acc1[ct][r];
        }
    }
}

// ---------------- k4: combine split-m quarters + ELU ----------------
__global__ void k4_combine(const float* __restrict__ U, const float* __restrict__ Z,
                           float* __restrict__ out) {
    long g = (long)blockIdx.x * 256 + threadIdx.x;   // float4 index
    long off = g * 4;
    long nf = off >> 7;                               // b*4096+n
    int b = (int)(nf >> 12), n = (int)(nf & 4095), col = (int)(off & 127);
    const long slice = (long)4096 * 128;
    long base0 = ((long)(b * 4) * 4096 + n) * 128 + col;
    f32x4 s = (f32x4)0.0f;
    float zz = 0.0f;
    #pragma unroll
    for (int i = 0; i < 4; ++i) {
        f32x4 u = *(const f32x4*)(U + base0 + i * slice);
        s += u;
        zz += Z[(b * 4 + i) * 4096 + n];
    }
    f32x4 v;
    #pragma unroll
    for (int i = 0; i < 4; ++i) {
        float x = s[i] / zz;
        v[i] = (x > 0.f) ? x : (expf(x) - 1.0f);
    }
    *(f32x4*)(out + off) = v;
}

extern "C" void kernel_launch(void* const* d_in, const int* in_sizes, int n_in,
                              void* d_out, int out_size, void* d_ws, size_t ws_size,
                              hipStream_t stream) {
    const float* h   = (const float*)d_in[0];
    const int*   adj = (const int*)d_in[1];
    const float* W   = (const float*)d_in[2];
    const float* a   = (const float*)d_in[3];
    float* out = (float*)d_out;

    char* ws = (char*)d_ws;
    short* WhT  = (short*)ws;                          // 4 MB  bf16 [b][col][n]
    short* WT   = (short*)(ws + 4194304);              // 64 KB bf16 [col][k]
    float* Wh1p = (float*)(ws + 4259840);              // 64 KB log2e*Wh@a1
    float* Tp   = (float*)(ws + 4325376);              // 64 KB log2e*Wh@a2
    float* Tmax = (float*)(ws + 4390912);              // 16 B (+pad)
    float* U    = (float*)(ws + 4391168);              // 32 MB (split=4)
    float* Z    = (float*)(ws + 4391168 + 33554432);   // 256 KB

    k0_wt<<<32, 256, 0, stream>>>(W, WT);
    k1_gemm<<<256, 256, 0, stream>>>(h, a, WT, WhT, Wh1p, Tp);
    k2_tmax<<<4, 256, 0, stream>>>(Tp, Tmax);
    k3_attn<4><<<512, 256, 0, stream>>>(adj, WhT, Wh1p, Tp, Tmax, U, Z);
    k4_combine<<<2048, 256, 0, stream>>>(U, Z, out);
    (void)in_sizes; (void)n_in; (void)out_size; (void)ws_size;
}

// Round 5
// 404.708 us; speedup vs baseline: 1.3067x; 1.2215x over previous
//
#include <hip/hip_runtime.h>
#include <hip/hip_bf16.h>
#include <math.h>

typedef __attribute__((ext_vector_type(4))) float  f32x4;
typedef __attribute__((ext_vector_type(4))) int    i32x4;
typedef __attribute__((ext_vector_type(8))) short  s16x8;
typedef __attribute__((ext_vector_type(4))) short  s16x4;
typedef __attribute__((ext_vector_type(8))) __bf16 bf16x8;

#define LOG2E 1.4426950408889634f

__device__ __forceinline__ short f32_to_bf16_rne(float f) {
    unsigned u = __builtin_bit_cast(unsigned, f);
    u += 0x7fffu + ((u >> 16) & 1u);
    return (short)(u >> 16);
}
__device__ __forceinline__ int pack2_bf16(float f0, float f1) {
    unsigned u0 = __builtin_bit_cast(unsigned, f0) + 0x8000u;   // round-half-up
    unsigned u1 = __builtin_bit_cast(unsigned, f1) + 0x8000u;
    return (int)((u0 >> 16) | (u1 & 0xffff0000u));
}
__device__ __forceinline__ bf16x8 as_bf16x8(s16x8 v) {
    return __builtin_bit_cast(bf16x8, v);
}
__device__ __forceinline__ bf16x8 as_bf16x8(i32x4 v) {
    return __builtin_bit_cast(bf16x8, v);
}

// ---------------- k0: W (f32 [k][col]) -> WT bf16 [col][k] ----------------
__global__ void k0_wt(const float* __restrict__ W, short* __restrict__ WT) {
    int g = blockIdx.x * 256 + threadIdx.x;     // 0..8191
    int col = g >> 6;
    int k0 = (g & 63) * 4;
    s16x4 v;
    #pragma unroll
    for (int i = 0; i < 4; ++i) v[i] = f32_to_bf16_rne(W[(k0 + i) * 128 + col]);
    *(s16x4*)(WT + col * 256 + k0) = v;
}

// ---------------- k1: Wh = h@W (MFMA), emit WhT bf16 [b][col][n], Wh1', Wh2' ----------------
__global__ __launch_bounds__(256, 2) void k1_gemm(
    const float* __restrict__ h, const float* __restrict__ a,
    const short* __restrict__ WT,
    short* __restrict__ WhT, float* __restrict__ Wh1p, float* __restrict__ Tp)
{
    int l = threadIdx.x & 63;
    int w = threadIdx.x >> 6;
    int gw = blockIdx.x * 4 + w;
    int r0 = gw * 16;                  // global row base (b*4096+n), multiple of 16
    int lm = l & 15, q = l >> 4;

    f32x4 acc[8];
    #pragma unroll
    for (int ct = 0; ct < 8; ++ct) acc[ct] = (f32x4)0.0f;

    const float* hrow = h + (long)(r0 + lm) * 256;
    for (int kb = 0; kb < 8; ++kb) {
        int kbase = kb * 32 + q * 8;
        f32x4 h0 = *(const f32x4*)(hrow + kbase);
        f32x4 h1 = *(const f32x4*)(hrow + kbase + 4);
        s16x8 af;
        #pragma unroll
        for (int j = 0; j < 4; ++j) af[j] = f32_to_bf16_rne(h0[j]);
        #pragma unroll
        for (int j = 0; j < 4; ++j) af[4 + j] = f32_to_bf16_rne(h1[j]);
        bf16x8 afb = as_bf16x8(af);
        #pragma unroll
        for (int ct = 0; ct < 8; ++ct) {
            s16x8 bf = *(const s16x8*)(WT + (ct * 16 + lm) * 256 + kbase);
            acc[ct] = __builtin_amdgcn_mfma_f32_16x16x32_bf16(afb, as_bf16x8(bf), acc[ct], 0, 0, 0);
        }
    }

    int b = r0 >> 12;
    int nb = r0 & 4095;
    float p1[4] = {0.f, 0.f, 0.f, 0.f}, p2[4] = {0.f, 0.f, 0.f, 0.f};
    #pragma unroll
    for (int ct = 0; ct < 8; ++ct) {
        int col = ct * 16 + lm;
        float a1c = a[col], a2c = a[128 + col];
        s16x4 vv;
        #pragma unroll
        for (int r = 0; r < 4; ++r) {
            float v = acc[ct][r];
            p1[r] += v * a1c;
            p2[r] += v * a2c;
            vv[r] = f32_to_bf16_rne(v);
        }
        *(s16x4*)(WhT + ((long)(b * 128 + col) * 4096 + nb + q * 4)) = vv;
    }
    #pragma unroll
    for (int off = 1; off < 16; off <<= 1) {
        #pragma unroll
        for (int r = 0; r < 4; ++r) {
            p1[r] += __shfl_xor(p1[r], off);
            p2[r] += __shfl_xor(p2[r], off);
        }
    }
    if (lm == 0) {
        #pragma unroll
        for (int r = 0; r < 4; ++r) {
            int row = r0 + q * 4 + r;
            Wh1p[row] = LOG2E * p1[r];
            Tp[row]   = LOG2E * p2[r];
        }
    }
}

// ---------------- k2: per-batch max of Tp ----------------
__global__ void k2_tmax(const float* __restrict__ Tp, float* __restrict__ Tmax) {
    __shared__ float red[256];
    int b = blockIdx.x, t = threadIdx.x;
    float mx = -1e30f;
    for (int i = 0; i < 16; ++i) mx = fmaxf(mx, Tp[b * 4096 + t + i * 256]);
    red[t] = mx;
    __syncthreads();
    for (int s = 128; s > 0; s >>= 1) {
        if (t < s) red[t] = fmaxf(red[t], red[t + s]);
        __syncthreads();
    }
    if (t == 0) Tmax[b] = red[0];
}

// ---------------- k3: LDS-dbuf attention; prefetches live ACROSS the barrier ----------------
// Per tile: issue glds(t+1 -> other buf) + adj(t+1 -> regs), compute(t), one barrier.
// Loads can't sink past __syncthreads -> they stay in flight during compute; the
// barrier's vmcnt(0) drain is then free. No VMEM inside compute (Tp staged in LDS)
// so nothing forces an early ordered-queue drain.
template <int SPLIT>
__global__ __launch_bounds__(256, 2) void k3_attn(
    const int* __restrict__ adj, const short* __restrict__ WhT,
    const float* __restrict__ Wh1p, const float* __restrict__ Tp,
    const float* __restrict__ Tmax,
    float* __restrict__ U, float* __restrict__ Z)
{
    const int MSLICE = 4096 / SPLIT;       // 2048
    const int MTILES = MSLICE / 128;       // 16
    __shared__ __align__(16) short tile[2][128 * 128];   // 64 KB B-tiles
    __shared__ __align__(16) float tps[4096 / SPLIT];    // 8 KB Tp slice

    int l = threadIdx.x & 63, w = threadIdx.x >> 6;
    int lm = l & 15, q = l >> 4;
    int bid = blockIdx.x;
    int mh = bid & (SPLIT - 1);
    int rg = (bid / SPLIT) & 63;
    int b  = bid / (SPLIT * 64);
    int n0 = rg * 64;
    int mbase = mh * MSLICE;

    int n_lane = n0 + w * 16 + lm;
    float sp = Wh1p[b * 4096 + n_lane];
    float xm = sp + Tmax[b];
    float Mrow = fmaxf(xm, 0.2f * xm);

    const int*   adjrow = adj + ((long)(b * 4096 + n_lane) << 12) + q * 8;
    const short* whtb   = WhT + (long)b * 128 * 4096;
    const float* tpsq   = tps + q * 8;

    // stage Tp slice to LDS (once)
    {
        const float* tg = Tp + b * 4096 + mbase;
        int i0 = threadIdx.x * 4;
        *(f32x4*)(tps + i0)        = *(const f32x4*)(tg + i0);
        *(f32x4*)(tps + i0 + 1024) = *(const f32x4*)(tg + i0 + 1024);
    }

    f32x4 acc[8];
    #pragma unroll
    for (int ct = 0; ct < 8; ++ct) acc[ct] = (f32x4)0.0f;
    float z = 0.0f;

    auto stage = [&](short* dst, int m0) {
        int colw = w * 32;
        #pragma unroll
        for (int j = 0; j < 8; ++j) {
            int cb = colw + j * 4;
            int col = cb + q;
            int gch = lm ^ (col & 7);
            const short* gp = whtb + (long)col * 4096 + m0 + gch * 8;
            __builtin_amdgcn_global_load_lds(
                (const __attribute__((address_space(1))) void*)gp,
                (__attribute__((address_space(3))) void*)(dst + cb * 128), 16, 0, 0);
        }
    };
    auto ldadj = [&](i32x4* aj, int m0) {
        #pragma unroll
        for (int ks = 0; ks < 4; ++ks) {
            aj[2 * ks]     = *(const i32x4*)(adjrow + m0 + ks * 32);
            aj[2 * ks + 1] = *(const i32x4*)(adjrow + m0 + ks * 32 + 4);
        }
    };
    auto compute = [&](const short* buf, const i32x4* aj, int mrel) {
        #pragma unroll
        for (int ks = 0; ks < 4; ++ks) {
            f32x4 t0 = *(const f32x4*)(tpsq + mrel + ks * 32);
            f32x4 t1 = *(const f32x4*)(tpsq + mrel + ks * 32 + 4);
            i32x4 pk;
            float zs = 0.0f;
            #pragma unroll
            for (int half = 0; half < 2; ++half) {
                i32x4 a4 = aj[2 * ks + half];
                f32x4 t4 = half ? t1 : t0;
                float wv[4];
                #pragma unroll
                for (int j = 0; j < 4; ++j) {
                    float y = sp + t4[j];
                    float e = fmaxf(y, 0.2f * y) - Mrow;
                    float v = __builtin_amdgcn_exp2f(e);
                    v = (a4[j] != 0) ? v : 0.0f;
                    zs += v; wv[j] = v;
                }
                pk[half * 2]     = pack2_bf16(wv[0], wv[1]);
                pk[half * 2 + 1] = pack2_bf16(wv[2], wv[3]);
            }
            z += zs;
            bf16x8 ab = as_bf16x8(pk);
            #pragma unroll
            for (int ct = 0; ct < 8; ++ct) {
                int col = ct * 16 + lm;
                int pos = (ks * 4 + q) ^ (col & 7);
                s16x8 bf = *(const s16x8*)(buf + col * 128 + pos * 8);
                acc[ct] = __builtin_amdgcn_mfma_f32_16x16x32_bf16(ab, as_bf16x8(bf), acc[ct], 0, 0, 0);
            }
        }
    };

    i32x4 ajA[8], ajB[8];
    stage(tile[0], mbase);
    ldadj(ajA, mbase);
    __syncthreads();

    #pragma unroll 1
    for (int t = 0; t < MTILES; t += 2) {
        int r1 = (t + 1) & (MTILES - 1);
        stage(tile[1], mbase + r1 * 128);
        ldadj(ajB, mbase + r1 * 128);
        __builtin_amdgcn_sched_barrier(0);
        compute(tile[0], ajA, t * 128);
        __syncthreads();
        int r2 = (t + 2) & (MTILES - 1);
        stage(tile[0], mbase + r2 * 128);
        ldadj(ajA, mbase + r2 * 128);
        __builtin_amdgcn_sched_barrier(0);
        compute(tile[1], ajB, r1 * 128);
        __syncthreads();
    }

    // z reduction over q (lanes lm, lm+16, lm+32, lm+48 hold partials of same row)
    z += __shfl_xor(z, 16);
    z += __shfl_xor(z, 32);

    int slice = b * SPLIT + mh;
    if (l < 16) Z[slice * 4096 + n0 + w * 16 + lm] = z;
    float* ub = U + ((long)slice * 4096 + n0 + w * 16) * 128;
    #pragma unroll
    for (int ct = 0; ct < 8; ++ct) {
        int col = ct * 16 + lm;
        #pragma unroll
        for (int r = 0; r < 4; ++r)
            ub[(q * 4 + r) * 128 + col] = acc[ct][r];
    }
}

// ---------------- k4: combine split-m halves + ELU ----------------
__global__ void k4_combine(const float* __restrict__ U, const float* __restrict__ Z,
                           float* __restrict__ out) {
    long g = (long)blockIdx.x * 256 + threadIdx.x;   // float4 index
    long off = g * 4;
    long nf = off >> 7;                               // b*4096+n
    int b = (int)(nf >> 12), n = (int)(nf & 4095), col = (int)(off & 127);
    long base0 = ((long)(b * 2) * 4096 + n) * 128 + col;
    f32x4 u0 = *(const f32x4*)(U + base0);
    f32x4 u1 = *(const f32x4*)(U + base0 + (long)4096 * 128);
    float zz = Z[(b * 2) * 4096 + n] + Z[(b * 2 + 1) * 4096 + n];
    f32x4 v;
    #pragma unroll
    for (int i = 0; i < 4; ++i) {
        float x = (u0[i] + u1[i]) / zz;
        v[i] = (x > 0.f) ? x : (expf(x) - 1.0f);
    }
    *(f32x4*)(out + off) = v;
}

extern "C" void kernel_launch(void* const* d_in, const int* in_sizes, int n_in,
                              void* d_out, int out_size, void* d_ws, size_t ws_size,
                              hipStream_t stream) {
    const float* h   = (const float*)d_in[0];
    const int*   adj = (const int*)d_in[1];
    const float* W   = (const float*)d_in[2];
    const float* a   = (const float*)d_in[3];
    float* out = (float*)d_out;

    char* ws = (char*)d_ws;
    short* WhT  = (short*)ws;                          // 4 MB  bf16 [b][col][n]
    short* WT   = (short*)(ws + 4194304);              // 64 KB bf16 [col][k]
    float* Wh1p = (float*)(ws + 4259840);              // 64 KB log2e*Wh@a1
    float* Tp   = (float*)(ws + 4325376);              // 64 KB log2e*Wh@a2
    float* Tmax = (float*)(ws + 4390912);              // 16 B (+pad)
    float* U    = (float*)(ws + 4391168);              // 16 MB (split=2)
    float* Z    = (float*)(ws + 4391168 + 16777216);   // 128 KB

    k0_wt<<<32, 256, 0, stream>>>(W, WT);
    k1_gemm<<<256, 256, 0, stream>>>(h, a, WT, WhT, Wh1p, Tp);
    k2_tmax<<<4, 256, 0, stream>>>(Tp, Tmax);
    k3_attn<2><<<512, 256, 0, stream>>>(adj, WhT, Wh1p, Tp, Tmax, U, Z);
    k4_combine<<<2048, 256, 0, stream>>>(U, Z, out);
    (void)in_sizes; (void)n_in; (void)out_size; (void)ws_size;
}